// Round 1
// baseline (1560.706 us; speedup 1.0000x reference)
//
#include <hip/hip_runtime.h>
#include <cstddef>

#define DEVINL __device__ __forceinline__

typedef __attribute__((ext_vector_type(8))) short bf16x8;
typedef __attribute__((ext_vector_type(4))) float f32x4;

DEVINL unsigned short f2bf(float f) {
  unsigned int u = __builtin_bit_cast(unsigned int, f);
  u += 0x7FFFu + ((u >> 16) & 1u);
  return (unsigned short)(u >> 16);
}

DEVINL float sigm(float x) { return 1.0f / (1.0f + __expf(-x)); }

// ---------------------------------------------------------------------------
// Node GEMMs: A = nf@Wg1^T, Bm = nf@Wg2^T, S = nf@Ws^T + bs, D = nf@Wd^T + bd
// (bias of Wg (bg) cancels under BN mean-subtraction; bs cancels too but kept)
// ---------------------------------------------------------------------------
__global__ __launch_bounds__(256) void node_gemm_k(
    const float* __restrict__ nf, const float* __restrict__ Wg,
    const float* __restrict__ Ws, const float* __restrict__ bs,
    const float* __restrict__ Wd, const float* __restrict__ bd,
    float* __restrict__ A, float* __restrict__ Bm,
    float* __restrict__ S, float* __restrict__ D, int N) {
  __shared__ float sNf[32 * 128];
  const int n0 = blockIdx.x * 32;
  for (int i = threadIdx.x; i < 1024; i += 256) {
    const int r = i >> 5, k = (i & 31) << 2;
    float4 v = make_float4(0.f, 0.f, 0.f, 0.f);
    if (n0 + r < N) v = *(const float4*)(nf + (size_t)(n0 + r) * 128 + k);
    *(float4*)(&sNf[r * 128 + k]) = v;
  }
  __syncthreads();
  const int c = threadIdx.x & 127, g = threadIdx.x >> 7;
  const float4* w0p = (const float4*)(Wg + (size_t)c * 384);
  const float4* w1p = (const float4*)(Wg + (size_t)c * 384 + 128);
  const float4* w2p = (const float4*)(Ws + (size_t)c * 128);
  const float4* w3p = (const float4*)(Wd + (size_t)c * 128);
  float a0[16], a1[16], a2[16], a3[16];
#pragma unroll
  for (int n = 0; n < 16; ++n) { a0[n] = 0.f; a1[n] = 0.f; a2[n] = 0.f; a3[n] = 0.f; }
#pragma unroll 4
  for (int k4 = 0; k4 < 32; ++k4) {
    const float4 w0 = w0p[k4], w1 = w1p[k4], w2 = w2p[k4], w3 = w3p[k4];
#pragma unroll
    for (int n = 0; n < 16; ++n) {
      const float4 x = *(const float4*)(&sNf[(g * 16 + n) * 128 + (k4 << 2)]);
      a0[n] += x.x * w0.x + x.y * w0.y + x.z * w0.z + x.w * w0.w;
      a1[n] += x.x * w1.x + x.y * w1.y + x.z * w1.z + x.w * w1.w;
      a2[n] += x.x * w2.x + x.y * w2.y + x.z * w2.z + x.w * w2.w;
      a3[n] += x.x * w3.x + x.y * w3.y + x.z * w3.z + x.w * w3.w;
    }
  }
  const float bsv = bs[c], bdv = bd[c];
#pragma unroll
  for (int n = 0; n < 16; ++n) {
    const int node = n0 + g * 16 + n;
    if (node < N) {
      const size_t o = (size_t)node * 128 + c;
      A[o] = a0[n];
      Bm[o] = a1[n];
      S[o] = a2[n] + bsv;
      D[o] = a3[n] + bdv;
    }
  }
}

// ---------------------------------------------------------------------------
// Edge pass: lin_nb[e,c] = (ef[e]@W3^T)[c] + A[src[e],c] + Bm[dst[e],c]
// STATS mode: accumulate per-feature sum/sumsq of lin_nb over all edges.
// APPLY mode: ue = silu(lin_nb*scale + shift); write ue; sg = sigmoid(ue);
//             agg[src] += sg; tacc[src] += sg * D[dst].
// MFMA 16x16x32 bf16. Block = 4 waves, 64 edges/tile; wave w -> edges [16w,16w+16),
// all 128 output features (8 c-tiles of 16).
// ---------------------------------------------------------------------------
template <bool APPLY>
__global__ __launch_bounds__(256) void edge_pass_k(
    const int* __restrict__ ei, const float* __restrict__ ef,
    const float* __restrict__ Wg,
    const float* __restrict__ A, const float* __restrict__ Bm,
    const float* __restrict__ D,
    const float* __restrict__ scaleE, const float* __restrict__ shiftE,
    float* __restrict__ esum, float* __restrict__ esq,
    float* __restrict__ agg, float* __restrict__ tacc,
    float* __restrict__ outE, int E, int numTiles) {
  __shared__ __align__(16) short sW[128 * 136];   // W3 bf16, pad 128->136 (2-way banks: free)
  __shared__ __align__(16) short sEf[64 * 136];   // ef tile bf16
  __shared__ int sIdx[128];                       // src[64], dst[64]

  const int tid = threadIdx.x;
  const int lane = tid & 63, wv = tid >> 6;
  const int l15 = lane & 15, quad = lane >> 4;
  const int r0 = wv << 4;
  const int* __restrict__ srcI = ei;
  const int* __restrict__ dstI = ei + E;

  // stage W3 = Wg[:,256:384] as bf16, once per block
  for (int i = tid; i < 4096; i += 256) {
    const int c = i >> 5, k = (i & 31) << 2;
    const float4 v = *(const float4*)(Wg + (size_t)c * 384 + 256 + k);
    const short4 s4 = make_short4((short)f2bf(v.x), (short)f2bf(v.y),
                                  (short)f2bf(v.z), (short)f2bf(v.w));
    *(short4*)(&sW[c * 136 + k]) = s4;
  }

  float scR[8], shR[8], sAc[8], qAc[8];
#pragma unroll
  for (int t = 0; t < 8; ++t) { sAc[t] = 0.f; qAc[t] = 0.f; }
  if (APPLY) {
#pragma unroll
    for (int t = 0; t < 8; ++t) {
      scR[t] = scaleE[t * 16 + l15];
      shR[t] = shiftE[t * 16 + l15];
    }
  }

  for (int tile = blockIdx.x; tile < numTiles; tile += gridDim.x) {
    const int e0 = tile << 6;
    __syncthreads();  // W3 ready (iter 0) / previous tile's LDS reads done
    if (tid < 64) sIdx[tid] = (e0 + tid < E) ? srcI[e0 + tid] : 0;
    else if (tid < 128) sIdx[tid] = (e0 + tid - 64 < E) ? dstI[e0 + tid - 64] : 0;
    for (int i = tid; i < 2048; i += 256) {
      const int r = i >> 5, k = (i & 31) << 2;
      const int e = e0 + r;
      float4 v = make_float4(0.f, 0.f, 0.f, 0.f);
      if (e < E) v = *(const float4*)(ef + (size_t)e * 128 + k);
      const short4 s4 = make_short4((short)f2bf(v.x), (short)f2bf(v.y),
                                    (short)f2bf(v.z), (short)f2bf(v.w));
      *(short4*)(&sEf[r * 136 + k]) = s4;
    }
    __syncthreads();

    f32x4 acc[8];
#pragma unroll
    for (int t = 0; t < 8; ++t) acc[t] = (f32x4){0.f, 0.f, 0.f, 0.f};
#pragma unroll
    for (int k0 = 0; k0 < 128; k0 += 32) {
      // A-frag: A[m = l15][k = k0 + quad*8 + j]  (edge rows)
      const bf16x8 a = *(const bf16x8*)(&sEf[(r0 + l15) * 136 + k0 + quad * 8]);
#pragma unroll
      for (int t = 0; t < 8; ++t) {
        // B-frag: B[k][n = l15] = W3[c = t*16+l15][k]  (weight rows, k-contiguous)
        const bf16x8 b = *(const bf16x8*)(&sW[(t * 16 + l15) * 136 + k0 + quad * 8]);
        acc[t] = __builtin_amdgcn_mfma_f32_16x16x32_bf16(a, b, acc[t], 0, 0, 0);
      }
    }

    // C/D layout: col = l15 (feature within c-tile), row = quad*4 + i (edge)
#pragma unroll
    for (int i = 0; i < 4; ++i) {
      const int rl = r0 + quad * 4 + i;
      const int e = e0 + rl;
      const bool valid = (e < E);
      const int sN = sIdx[rl], dN = sIdx[64 + rl];
      const float* __restrict__ Ar = A + (size_t)sN * 128;
      const float* __restrict__ Br = Bm + (size_t)dN * 128;
#pragma unroll
      for (int t = 0; t < 8; ++t) {
        const int c = t * 16 + l15;
        const float lin = acc[t][i] + Ar[c] + Br[c];
        if (APPLY) {
          if (valid) {
            const float y = lin * scR[t] + shR[t];
            const float ue = y * sigm(y);
            outE[(size_t)e * 128 + c] = ue;
            const float sg = sigm(ue);
            unsafeAtomicAdd(&agg[(size_t)sN * 128 + c], sg);
            const float gd = D[(size_t)dN * 128 + c];
            unsafeAtomicAdd(&tacc[(size_t)sN * 128 + c], sg * gd);
          }
        } else {
          if (valid) { sAc[t] += lin; qAc[t] += lin * lin; }
        }
      }
    }
  }

  if (!APPLY) {
    __syncthreads();
    float* red = (float*)sEf;  // reuse: 1024 floats
#pragma unroll
    for (int t = 0; t < 8; ++t) {
      float s = sAc[t], q = qAc[t];
      s += __shfl_xor(s, 16); s += __shfl_xor(s, 32);
      q += __shfl_xor(q, 16); q += __shfl_xor(q, 32);
      if (quad == 0) {
        red[wv * 128 + t * 16 + l15] = s;
        red[512 + wv * 128 + t * 16 + l15] = q;
      }
    }
    __syncthreads();
    if (tid < 128) {
      const float s = red[tid] + red[128 + tid] + red[256 + tid] + red[384 + tid];
      const float q = red[512 + tid] + red[640 + tid] + red[768 + tid] + red[896 + tid];
      unsafeAtomicAdd(&esum[tid], s);
      unsafeAtomicAdd(&esq[tid], q);
    }
  }
}

// ---------------------------------------------------------------------------
__global__ __launch_bounds__(128) void finalize_bn_k(
    const float* __restrict__ sum, const float* __restrict__ sq,
    const float* __restrict__ gamma, const float* __restrict__ beta,
    float inv_cnt, float* __restrict__ scale, float* __restrict__ shift) {
  const int c = threadIdx.x;
  const float mean = sum[c] * inv_cnt;
  const float var = sq[c] * inv_cnt - mean * mean;
  const float sc = gamma[c] * rsqrtf(var + 1e-5f);
  scale[c] = sc;
  shift[c] = beta[c] - mean * sc;
}

// hvec = S + tacc/(agg+eps); accumulate per-feature BN stats over nodes
__global__ __launch_bounds__(256) void node_combine_k(
    const float* __restrict__ S, const float* __restrict__ T, const float* __restrict__ AG,
    float* __restrict__ hvec, float* __restrict__ nsum, float* __restrict__ nsq, int total) {
  float ps = 0.f, pq = 0.f;
  const int stride = gridDim.x * 256;
  for (int idx = blockIdx.x * 256 + threadIdx.x; idx < total; idx += stride) {
    const float hv = S[idx] + T[idx] / (AG[idx] + 1e-6f);
    hvec[idx] = hv;
    ps += hv; pq += hv * hv;
  }
  // thread's feature is fixed: h = tid & 127 (stride % 128 == 0)
  __shared__ float red[512];
  red[threadIdx.x] = ps;
  red[256 + threadIdx.x] = pq;
  __syncthreads();
  if (threadIdx.x < 128) {
    const int h = threadIdx.x;
    unsafeAtomicAdd(&nsum[h], red[h] + red[h + 128]);
    unsafeAtomicAdd(&nsq[h], red[256 + h] + red[384 + h]);
  }
}

__global__ __launch_bounds__(256) void node_out_k(
    const float* __restrict__ nf, const float* __restrict__ hvec,
    const float* __restrict__ scale, const float* __restrict__ shift,
    float* __restrict__ out, int total) {
  const int stride = gridDim.x * 256;
  for (int idx = blockIdx.x * 256 + threadIdx.x; idx < total; idx += stride) {
    const int h = idx & 127;
    const float y = hvec[idx] * scale[h] + shift[h];
    out[idx] = nf[idx] + y * sigm(y);
  }
}

// ---------------------------------------------------------------------------
extern "C" void kernel_launch(void* const* d_in, const int* in_sizes, int n_in,
                              void* d_out, int out_size, void* d_ws, size_t ws_size,
                              hipStream_t stream) {
  const int* ei = (const int*)d_in[0];
  const float* nf = (const float*)d_in[1];
  const float* ef = (const float*)d_in[2];
  const float* Wg = (const float*)d_in[3];
  // d_in[4] = bg : cancels exactly under BN mean subtraction — unused
  const float* Ws = (const float*)d_in[5];
  const float* bs = (const float*)d_in[6];
  const float* Wd = (const float*)d_in[7];
  const float* bd = (const float*)d_in[8];
  const float* zg = (const float*)d_in[9];
  const float* zb = (const float*)d_in[10];
  const float* ng = (const float*)d_in[11];
  const float* nb = (const float*)d_in[12];

  const int N = in_sizes[1] / 128;
  const int E = in_sizes[2] / 128;
  const size_t NH = (size_t)N * 128;

  float* ws = (float*)d_ws;
  float* A    = ws;
  float* Bm   = A + NH;
  float* S    = Bm + NH;
  float* D    = S + NH;
  float* hvec = D + NH;
  float* agg  = hvec + NH;
  float* tac  = agg + NH;
  float* st   = tac + NH;  // 1024 floats of stats/params
  float* esum = st;
  float* esq  = st + 128;
  float* nsum = st + 256;
  float* nsq  = st + 384;
  float* scE  = st + 512;
  float* shE  = st + 640;
  float* scN  = st + 768;
  float* shN  = st + 896;

  float* outN = (float*)d_out;
  float* outE = outN + NH;

  // zero: agg, tac, and the 4 stat accumulators (contiguous)
  hipMemsetAsync(agg, 0, (2 * NH + 512) * sizeof(float), stream);

  node_gemm_k<<<(N + 31) / 32, 256, 0, stream>>>(nf, Wg, Ws, bs, Wd, bd, A, Bm, S, D, N);

  const int numTiles = (E + 63) / 64;
  const int gblocks = numTiles < 1280 ? numTiles : 1280;
  edge_pass_k<false><<<gblocks, 256, 0, stream>>>(
      ei, ef, Wg, A, Bm, nullptr, nullptr, nullptr,
      esum, esq, nullptr, nullptr, nullptr, E, numTiles);
  finalize_bn_k<<<1, 128, 0, stream>>>(esum, esq, zg, zb, 1.0f / (float)E, scE, shE);
  edge_pass_k<true><<<gblocks, 256, 0, stream>>>(
      ei, ef, Wg, A, Bm, D, scE, shE,
      nullptr, nullptr, agg, tac, outE, E, numTiles);
  node_combine_k<<<640, 256, 0, stream>>>(S, tac, agg, hvec, nsum, nsq, (int)NH);
  finalize_bn_k<<<1, 128, 0, stream>>>(nsum, nsq, ng, nb, 1.0f / (float)N, scN, shN);
  node_out_k<<<640, 256, 0, stream>>>(nf, hvec, scN, shN, outN, (int)NH);
}